// Round 4
// baseline (608.540 us; speedup 1.0000x reference)
//
#include <hip/hip_runtime.h>
#include <math.h>

// ---------------------------------------------------------------------------
// GATv2 x3 + LN + graph max-pool + MLP.
// Round 13: k_agg re-decomposed. Evidence R10-R12: schedule-level changes
// (prefetch depth 1/2/3, sched_barrier pinning) all flat -> stall fraction
// immovable; counter arithmetic implies ~56 VALU/edge vs ~14 ideal. Fix the
// decomposition: 4 edges/iter x 16 lanes x 8ch (was 2 x 32 x 4ch):
//  - iterations halve -> loop ctl / exp2 / reduce amortize 2x
//  - score reduce: head = 4 lanes -> 2 quad-perm DPP ops
//  - gathers dwordx4 (16B/lane), records 1 load / 4 edges
//  - LN reductions all-DPP (quad xor1/xor2, row_half_mirror, row_mirror);
//    group combine = ds_swizzle xor16 + shfl_xor 32, once per wave
// k_pack layout updated to tab[l][sub16][32] = {wea[8],web[8],wec[8],att[8]}.
// e4 keeps +8 pad records (quad overrun reads are valid, masked by wgt=0).
// Everything else unchanged.
// ---------------------------------------------------------------------------

#define LN_EPS 1e-5f
#define LOG2E 1.44269504088896340736f
#define CHUNK 4096
#define BCAP 8192  // records per staging bucket (avg 4096)

typedef short bf16x8 __attribute__((ext_vector_type(8)));
typedef float f32x4 __attribute__((ext_vector_type(4)));
typedef float f32x2 __attribute__((ext_vector_type(2)));

static __device__ __forceinline__ unsigned short f2bf(float f) {
  unsigned int u = __float_as_uint(f);
  u += 0x7fffu + ((u >> 16) & 1u);  // RNE
  return (unsigned short)(u >> 16);
}

template <int CTRL>
static __device__ __forceinline__ float dpp_add(float v) {
  int x = __builtin_amdgcn_update_dpp(0, __float_as_int(v), CTRL, 0xf, 0xf, true);
  return v + __int_as_float(x);
}

// sum+broadcast over each 4-lane quad (score reduce: one head = 4 lanes)
static __device__ __forceinline__ float dpp_sum4(float v) {
  v = dpp_add<0x0B1>(v);  // quad_perm 1,0,3,2  (xor1)
  v = dpp_add<0x04E>(v);  // quad_perm 2,3,0,1  (xor2)
  return v;
}

// sum+broadcast over each 16-lane row. Valid by progressive uniformity:
// after xor1+xor2 quads are uniform -> row_half_mirror supplies the other
// quad; after that 8-groups are uniform -> row_mirror supplies the other 8.
static __device__ __forceinline__ float dpp_sum16(float v) {
  v = dpp_add<0x0B1>(v);
  v = dpp_add<0x04E>(v);
  v = dpp_add<0x141>(v);  // row_half_mirror
  v = dpp_add<0x140>(v);  // row_mirror
  return v;
}

// lane^16 within each 32-lane half (BitMode: xor=0x10, and=0x1F)
static __device__ __forceinline__ float swz16(float v) {
  return __int_as_float(__builtin_amdgcn_ds_swizzle(__float_as_int(v), 0x401F));
}

// ---------------- binned CSR build ----------------

__global__ __launch_bounds__(256) void k_binA(const int* __restrict__ ei, const float* __restrict__ ea,
                                              int* __restrict__ gcnt, float4* __restrict__ staged,
                                              int E, int nbuk) {
  __shared__ int hist[256];
  __shared__ int basebuf[256];
  int t = threadIdx.x;
  int e0 = blockIdx.x * CHUNK;

  hist[t] = 0;
  __syncthreads();
#pragma unroll
  for (int i = 0; i < CHUNK / 256; ++i) {
    int e = e0 + i * 256 + t;
    if (e < E) atomicAdd(&hist[ei[E + e] >> 8], 1);
  }
  __syncthreads();
  int h = hist[t];
  if (t < nbuk && h > 0) basebuf[t] = t * BCAP + atomicAdd(&gcnt[t], h);
  hist[t] = 0;
  __syncthreads();
#pragma unroll
  for (int i = 0; i < CHUNK / 256; ++i) {
    int e = e0 + i * 256 + t;
    if (e < E) {
      int s = ei[e];
      int d = ei[E + e];
      int b = d >> 8;
      int r = atomicAdd(&hist[b], 1);
      float4 rec;
      rec.x = ea[e * 3 + 0];
      rec.y = ea[e * 3 + 1];
      rec.z = ea[e * 3 + 2];
      rec.w = __int_as_float(s | (d << 16));
      staged[basebuf[b] + r] = rec;
    }
  }
}

__global__ void k_bscan(const int* __restrict__ gcnt, int* __restrict__ bukStart,
                        int* __restrict__ offs, float4* __restrict__ e4,
                        int N, int nbuk, int EP) {
  __shared__ int sh[256];
  int t = threadIdx.x;
  int nodes = (t < nbuk) ? min(256, N - t * 256) : 0;
  int v = (t < nbuk) ? gcnt[t] + nodes : 0;
  sh[t] = v;
  __syncthreads();
  for (int d = 1; d < 256; d <<= 1) {
    int add = (t >= d) ? sh[t - d] : 0;
    __syncthreads();
    sh[t] += add;
    __syncthreads();
  }
  if (t < nbuk) bukStart[t] = sh[t] - v;
  if (t == 0) offs[N] = EP;
  // pad records past EP: valid gather offset (row 0), finite attrs; absorb
  // quad-pipeline overrun reads from the last node without clamps.
  if (t < 8) {
    float4 r;
    r.x = 0.f; r.y = 0.f; r.z = 0.f;
    r.w = __int_as_float(0);
    e4[EP + t] = r;
  }
}

__global__ __launch_bounds__(256) void k_binB(const float4* __restrict__ staged,
                                              const int* __restrict__ gcnt,
                                              const int* __restrict__ bukStart,
                                              float4* __restrict__ e4,
                                              int* __restrict__ offs, int N) {
  __shared__ int hist[256], cur[256], begS[256], sh[256];
  int t = threadIdx.x;
  int b = blockIdx.x;
  int n0 = b * 256;
  int nn = min(256, N - n0);
  int m = gcnt[b];
  size_t sbase = (size_t)b * BCAP;

  hist[t] = 0;
  __syncthreads();
  for (int p = t; p < m; p += 256) {
    unsigned int u = (unsigned int)__float_as_int(staged[sbase + p].w);
    atomicAdd(&hist[(int)(u >> 16) - n0], 1);
  }
  __syncthreads();
  int v = (t < nn) ? hist[t] + 1 : 0;
  sh[t] = v;
  __syncthreads();
  for (int d = 1; d < 256; d <<= 1) {
    int add = (t >= d) ? sh[t - d] : 0;
    __syncthreads();
    sh[t] += add;
    __syncthreads();
  }
  if (t < nn) {
    int base = bukStart[b] + sh[t] - v;
    cur[t] = base;
    begS[t] = base;
    offs[n0 + t] = base;
  }
  __syncthreads();
  for (int p = t; p < m; p += 256) {
    float4 rec = staged[sbase + p];
    unsigned int u = (unsigned int)__float_as_int(rec.w);
    int pos = atomicAdd(&cur[(int)(u >> 16) - n0], 1);
    rec.w = __int_as_float((int)(u & 0xffffu) * 256);
    e4[pos] = rec;
  }
  __syncthreads();
  if (t < nn) {
    int beg = begS[t], last = cur[t];  // cur == self-loop slot after placement
    float s0 = 0.f, s1 = 0.f, s2 = 0.f;
    for (int p = beg; p < last; ++p) {
      float4 r = e4[p];
      s0 += r.x;
      s1 += r.y;
      s2 += r.z;
    }
    float invc = 1.0f / fmaxf((float)(last - beg), 1.0f);
    float4 r;
    r.x = s0 * invc;
    r.y = s1 * invc;
    r.z = s2 * invc;
    r.w = __int_as_float((n0 + t) * 256);
    e4[last] = r;
  }
}

// ---------------- converters / param packing ----------------

__global__ void k_convx(const float* __restrict__ x, unsigned short* __restrict__ xb, int n) {
  int i = (blockIdx.x * blockDim.x + threadIdx.x) * 4;
  if (i >= n) return;
  float4 v = *(const float4*)&x[i];
  ushort4 o;
  o.x = f2bf(v.x); o.y = f2bf(v.y); o.z = f2bf(v.z); o.w = f2bf(v.w);
  *(ushort4*)&xb[i] = o;
}

__global__ void k_convW(const float* __restrict__ w0, const float* __restrict__ w1,
                        const float* __restrict__ w2, const float* __restrict__ w3,
                        const float* __restrict__ w4, const float* __restrict__ w5,
                        unsigned short* __restrict__ dst) {
  const float* srcs[6] = {w0, w1, w2, w3, w4, w5};
  const float* s = srcs[blockIdx.y];
  int i = blockIdx.x * 256 + threadIdx.x;  // 0..16383
  dst[(size_t)blockIdx.y * 16384 + i] = f2bf(s[i]);
}

// per-layer, per-sublane score params: tab[l][sub][32] = {wea[8], web[8], wec[8], att*LOG2E[8]}
// sub in [0,16); channel block = sub*8 + j
__global__ void k_pack(const float* __restrict__ We0, const float* __restrict__ att0,
                       const float* __restrict__ We1, const float* __restrict__ att1,
                       const float* __restrict__ We2, const float* __restrict__ att2,
                       float* __restrict__ tab) {
  int l = blockIdx.x;   // 3
  int t = threadIdx.x;  // 16 (= sub)
  const float* We = (l == 0) ? We0 : ((l == 1) ? We1 : We2);
  const float* att = (l == 0) ? att0 : ((l == 1) ? att1 : att2);
  float* o = tab + (size_t)l * 512 + t * 32;
#pragma unroll
  for (int j = 0; j < 8; ++j) {
    int ch = t * 8 + j;
    o[j] = We[ch * 3 + 0];
    o[8 + j] = We[ch * 3 + 1];
    o[16 + j] = We[ch * 3 + 2];
    o[24 + j] = att[ch] * LOG2E;
  }
}

// ---------------- MFMA GEMM (swapped operands): out_bf16[n][j] = bias[j] + x[n]·W[j] ----------------
__global__ __launch_bounds__(256) void k_gemm_mfma(const unsigned short* __restrict__ xb,
                                                   const unsigned short* __restrict__ Wb,
                                                   const float* __restrict__ bl, const float* __restrict__ br,
                                                   unsigned short* __restrict__ xlb,
                                                   unsigned short* __restrict__ xrb, int N) {
  int wave = threadIdx.x >> 6;
  int lane = threadIdx.x & 63;
  int which = blockIdx.y;
  const unsigned short* W = Wb + (size_t)which * 16384;
  const float* bias = which ? br : bl;
  unsigned short* out = which ? xrb : xlb;

  int row0 = (blockIdx.x * 4 + wave) * 16;
  if (row0 >= N) return;
  int m = lane & 15;
  int q = lane >> 4;

  int brow = row0 + m;
  if (brow >= N) brow = N - 1;
  const unsigned short* xrow = xb + (size_t)brow * 128 + q * 8;

  bf16x8 bfrag[4];
#pragma unroll
  for (int kt = 0; kt < 4; ++kt) bfrag[kt] = *(const bf16x8*)(xrow + kt * 32);

  f32x4 acc[8];
#pragma unroll
  for (int jt = 0; jt < 8; ++jt) acc[jt] = (f32x4){0.f, 0.f, 0.f, 0.f};

  const unsigned short* wbase = W + (size_t)m * 128 + q * 8;
#pragma unroll
  for (int kt = 0; kt < 4; ++kt) {
#pragma unroll
    for (int jt = 0; jt < 8; ++jt) {
      bf16x8 a = *(const bf16x8*)(wbase + (size_t)jt * 16 * 128 + kt * 32);
      acc[jt] = __builtin_amdgcn_mfma_f32_16x16x32_bf16(a, bfrag[kt], acc[jt], 0, 0, 0);
    }
  }

  int node = row0 + m;
  if (node < N) {
    unsigned short* orow = out + (size_t)node * 128 + q * 4;
#pragma unroll
    for (int jt = 0; jt < 8; ++jt) {
      float4 bs = *(const float4*)&bias[jt * 16 + q * 4];
      uint2 pack;
      pack.x = (unsigned int)f2bf(acc[jt][0] + bs.x) | ((unsigned int)f2bf(acc[jt][1] + bs.y) << 16);
      pack.y = (unsigned int)f2bf(acc[jt][2] + bs.z) | ((unsigned int)f2bf(acc[jt][3] + bs.w) << 16);
      *(uint2*)(orow + jt * 16) = pack;
    }
  }
}

// ---------------- fused: score + softmax(exp2) + weighted agg + epilogue ----------------
// one wave per node; 4 edge slots (g = lane>>4), 16 lanes each; lane owns
// 8 channels ch = (lane&15)*8. Head = 32 ch = 4 consecutive sub-lanes (quad).
__global__ __launch_bounds__(256) void k_agg(const unsigned short* __restrict__ xlb,
                                             const unsigned short* __restrict__ xrb,
                                             const float4* __restrict__ e4,
                                             const int* __restrict__ offs,
                                             const float* __restrict__ scoreTab,
                                             const float* __restrict__ bo,
                                             const float* __restrict__ lng, const float* __restrict__ lnb,
                                             unsigned short* __restrict__ xnext_bf,
                                             float* __restrict__ emb, int last, int N) {
  int w = (blockIdx.x * blockDim.x + threadIdx.x) >> 6;
  if (w >= N) return;
  int lane = threadIdx.x & 63;
  int g = lane >> 4;    // edge slot
  int sub = lane & 15;  // channel block
  unsigned int cOff = (unsigned int)(sub * 16);  // byte offset in 256B bf16 row
  int beg = offs[w], end = offs[w + 1];
  int cnt = end - beg;

  // per-lane params: 8 channels as 4 f32x2
  f32x2 wea[4], web[4], wec[4], at[4], xr[4];
  {
    const float4* tp = (const float4*)(scoreTab + (size_t)sub * 32);
    float4 a0 = tp[0], a1 = tp[1], b0 = tp[2], b1 = tp[3];
    float4 c0 = tp[4], c1 = tp[5], t0 = tp[6], t1 = tp[7];
    wea[0] = (f32x2){a0.x, a0.y}; wea[1] = (f32x2){a0.z, a0.w};
    wea[2] = (f32x2){a1.x, a1.y}; wea[3] = (f32x2){a1.z, a1.w};
    web[0] = (f32x2){b0.x, b0.y}; web[1] = (f32x2){b0.z, b0.w};
    web[2] = (f32x2){b1.x, b1.y}; web[3] = (f32x2){b1.z, b1.w};
    wec[0] = (f32x2){c0.x, c0.y}; wec[1] = (f32x2){c0.z, c0.w};
    wec[2] = (f32x2){c1.x, c1.y}; wec[3] = (f32x2){c1.z, c1.w};
    at[0] = (f32x2){t0.x, t0.y}; at[1] = (f32x2){t0.z, t0.w};
    at[2] = (f32x2){t1.x, t1.y}; at[3] = (f32x2){t1.z, t1.w};
    uint4 vr = *(const uint4*)((const char*)xrb + (size_t)w * 256 + cOff);
    xr[0][0] = __uint_as_float(vr.x << 16); xr[0][1] = __uint_as_float(vr.x & 0xffff0000u);
    xr[1][0] = __uint_as_float(vr.y << 16); xr[1][1] = __uint_as_float(vr.y & 0xffff0000u);
    xr[2][0] = __uint_as_float(vr.z << 16); xr[2][1] = __uint_as_float(vr.z & 0xffff0000u);
    xr[3][0] = __uint_as_float(vr.w << 16); xr[3][1] = __uint_as_float(vr.w & 0xffff0000u);
  }

  const char* e4B = (const char*)e4;
  const char* xlB = (const char*)xlb + cOff;

  float l = 0.f;
  f32x2 acc[4] = {(f32x2){0.f, 0.f}, (f32x2){0.f, 0.f}, (f32x2){0.f, 0.f}, (f32x2){0.f, 0.f}};

  int Tq = (cnt + 3) >> 2;  // quad iterations

  // one edge per 16-lane group: unpack gather, packed score, quad-reduce,
  // exp2, masked accumulate. msk is 1.0 (valid) or 0.0.
  auto compute = [&](const float4& e, uint4 v, float msk) {
    f32x2 xl[4];
    xl[0][0] = __uint_as_float(v.x << 16); xl[0][1] = __uint_as_float(v.x & 0xffff0000u);
    xl[1][0] = __uint_as_float(v.y << 16); xl[1][1] = __uint_as_float(v.y & 0xffff0000u);
    xl[2][0] = __uint_as_float(v.z << 16); xl[2][1] = __uint_as_float(v.z & 0xffff0000u);
    xl[3][0] = __uint_as_float(v.w << 16); xl[3][1] = __uint_as_float(v.w & 0xffff0000u);
    f32x2 ex = {e.x, e.x}, ey = {e.y, e.y}, ez = {e.z, e.z};
    f32x2 part = {0.f, 0.f};
#pragma unroll
    for (int j = 0; j < 4; ++j) {
      f32x2 t = __builtin_elementwise_fma(wea[j], ex,
                  __builtin_elementwise_fma(web[j], ey,
                    __builtin_elementwise_fma(wec[j], ez, xr[j] + xl[j])));
      t = __builtin_elementwise_max(t, t * 0.2f);
      part = __builtin_elementwise_fma(t, at[j], part);
    }
    float s = dpp_sum4(part[0] + part[1]);  // head sum (4 sub-lanes)
    float wgt = __builtin_amdgcn_exp2f(s) * msk;
    l += wgt;
    f32x2 w2 = {wgt, wgt};
#pragma unroll
    for (int j = 0; j < 4; ++j) acc[j] = __builtin_elementwise_fma(xl[j], w2, acc[j]);
  };

  unsigned int o = (unsigned int)(beg + g) << 4;  // this slot's record
  float4 eC = *(const float4*)(e4B + o);
#pragma unroll 2
  for (int it = 0; it < Tq - 1; ++it) {
    uint4 v = *(const uint4*)(xlB + (unsigned int)__float_as_int(eC.w));
    float4 eN = *(const float4*)(e4B + o + 64u);
    o += 64u;
    compute(eC, v, 1.f);
    eC = eN;
  }
  {  // final quad (masked)
    uint4 v = *(const uint4*)(xlB + (unsigned int)__float_as_int(eC.w));
    float msk = (4 * (Tq - 1) + g < cnt) ? 1.f : 0.f;
    compute(eC, v, msk);
  }

  // combine the 4 edge-slot groups: xor16 (ds_swizzle) then xor32 (shfl)
  float a0 = acc[0][0], a1 = acc[0][1], a2 = acc[1][0], a3 = acc[1][1];
  float a4 = acc[2][0], a5 = acc[2][1], a6 = acc[3][0], a7 = acc[3][1];
  l += swz16(l); l += __shfl_xor(l, 32);
  a0 += swz16(a0); a0 += __shfl_xor(a0, 32);
  a1 += swz16(a1); a1 += __shfl_xor(a1, 32);
  a2 += swz16(a2); a2 += __shfl_xor(a2, 32);
  a3 += swz16(a3); a3 += __shfl_xor(a3, 32);
  a4 += swz16(a4); a4 += __shfl_xor(a4, 32);
  a5 += swz16(a5); a5 += __shfl_xor(a5, 32);
  a6 += swz16(a6); a6 += __shfl_xor(a6, 32);
  a7 += swz16(a7); a7 += __shfl_xor(a7, 32);

  float inv = 1.0f / l;
  const float4 bo0 = *(const float4*)&bo[sub * 8];
  const float4 bo1 = *(const float4*)&bo[sub * 8 + 4];
  float o0 = a0 * inv + bo0.x, o1 = a1 * inv + bo0.y;
  float o2 = a2 * inv + bo0.z, o3 = a3 * inv + bo0.w;
  float o4 = a4 * inv + bo1.x, o5 = a5 * inv + bo1.y;
  float o6 = a6 * inv + bo1.z, o7 = a7 * inv + bo1.w;

  if (last) {
    if (g == 0) {
      float* er = &emb[(size_t)w * 128 + sub * 8];
      *(float4*)er = (float4){o0, o1, o2, o3};
      *(float4*)(er + 4) = (float4){o4, o5, o6, o7};
    }
  } else {
    float r0 = fmaxf(o0, 0.f), r1 = fmaxf(o1, 0.f), r2 = fmaxf(o2, 0.f), r3 = fmaxf(o3, 0.f);
    float r4 = fmaxf(o4, 0.f), r5 = fmaxf(o5, 0.f), r6 = fmaxf(o6, 0.f), r7 = fmaxf(o7, 0.f);
    float s = ((r0 + r1) + (r2 + r3)) + ((r4 + r5) + (r6 + r7));
    s = dpp_sum16(s);  // sum over 16 sub-lanes (values group-uniform)
    float mu = s * 0.0078125f;  // /128
    float d0 = r0 - mu, d1 = r1 - mu, d2 = r2 - mu, d3 = r3 - mu;
    float d4 = r4 - mu, d5 = r5 - mu, d6 = r6 - mu, d7 = r7 - mu;
    float v2 = ((d0 * d0 + d1 * d1) + (d2 * d2 + d3 * d3)) +
               ((d4 * d4 + d5 * d5) + (d6 * d6 + d7 * d7));
    v2 = dpp_sum16(v2);
    float rstd = rsqrtf(v2 * 0.0078125f + LN_EPS);
    if (g == 0) {
      const float4 g0v = *(const float4*)&lng[sub * 8];
      const float4 g1v = *(const float4*)&lng[sub * 8 + 4];
      const float4 b0v = *(const float4*)&lnb[sub * 8];
      const float4 b1v = *(const float4*)&lnb[sub * 8 + 4];
      float y0 = d0 * rstd * g0v.x + b0v.x;
      float y1 = d1 * rstd * g0v.y + b0v.y;
      float y2 = d2 * rstd * g0v.z + b0v.z;
      float y3 = d3 * rstd * g0v.w + b0v.w;
      float y4 = d4 * rstd * g1v.x + b1v.x;
      float y5 = d5 * rstd * g1v.y + b1v.y;
      float y6 = d6 * rstd * g1v.z + b1v.z;
      float y7 = d7 * rstd * g1v.w + b1v.w;
      uint4 pack;
      pack.x = (unsigned int)f2bf(y0) | ((unsigned int)f2bf(y1) << 16);
      pack.y = (unsigned int)f2bf(y2) | ((unsigned int)f2bf(y3) << 16);
      pack.z = (unsigned int)f2bf(y4) | ((unsigned int)f2bf(y5) << 16);
      pack.w = (unsigned int)f2bf(y6) | ((unsigned int)f2bf(y7) << 16);
      *(uint4*)&xnext_bf[(size_t)w * 128 + sub * 8] = pack;
    }
  }
}

// ---------------- graph max-pool (relu implicit: atomicMax vs 0-init) ----------------
__global__ void k_pool(const float* __restrict__ emb, const int* __restrict__ batch,
                       float* __restrict__ pooled, int N) {
  int c = threadIdx.x & 127;
  int half = threadIdx.x >> 7;
  int base = blockIdx.x * 64 + half;
  int limit = min(blockIdx.x * 64 + 64, N);
  float cur = 0.f;
  int curg = -1;
  for (int n = base; n < limit; n += 2) {
    int g = batch[n];
    if (g != curg) {
      if (curg >= 0) atomicMax((unsigned int*)&pooled[curg * 128 + c], __float_as_uint(cur));
      curg = g;
      cur = 0.f;
    }
    cur = fmaxf(cur, emb[(size_t)n * 128 + c]);
  }
  if (curg >= 0) atomicMax((unsigned int*)&pooled[curg * 128 + c], __float_as_uint(cur));
}

// ---------------- MLP: 128 -> 32 -> 32 -> 32 -> 1 ----------------
__global__ void k_mlp(const float* __restrict__ pooled,
                      const float* __restrict__ pw1, const float* __restrict__ pb1,
                      const float* __restrict__ pw2, const float* __restrict__ pb2,
                      const float* __restrict__ pw3, const float* __restrict__ pb3,
                      const float* __restrict__ pw4, const float* __restrict__ pb4,
                      float* __restrict__ out) {
  int g = blockIdx.x;
  int t = threadIdx.x;  // 64 threads
  __shared__ float buf1[32], buf2[32];
  if (t < 32) {
    float acc = pb1[t];
    for (int k = 0; k < 128; ++k) acc += pw1[t * 128 + k] * pooled[g * 128 + k];
    buf1[t] = fmaxf(acc, 0.f);
  }
  __syncthreads();
  if (t < 32) {
    float acc = pb2[t];
    for (int k = 0; k < 32; ++k) acc += pw2[t * 32 + k] * buf1[k];
    buf2[t] = fmaxf(acc, 0.f);
  }
  __syncthreads();
  if (t < 32) {
    float acc = pb3[t];
    for (int k = 0; k < 32; ++k) acc += pw3[t * 32 + k] * buf2[k];
    buf1[t] = fmaxf(acc, 0.f);
  }
  __syncthreads();
  if (t == 0) {
    float acc = pb4[0];
    for (int k = 0; k < 32; ++k) acc += pw4[k] * buf1[k];
    out[g] = acc;
  }
}

// ---------------------------------------------------------------------------

extern "C" void kernel_launch(void* const* d_in, const int* in_sizes, int n_in,
                              void* d_out, int out_size, void* d_ws, size_t ws_size,
                              hipStream_t stream) {
  const float* x_in = (const float*)d_in[0];
  const int* ei = (const int*)d_in[1];
  const int* batch = (const int*)d_in[2];
  const float* ea = (const float*)d_in[3];

  const int N = in_sizes[0] / 128;
  const int E = in_sizes[1] / 2;
  const int EP = E + N;
  const int G = out_size - N * 128;
  const int NBUK = (N + 255) / 256;

  const float *Wl[3], *bl[3], *Wr[3], *br[3], *We[3], *att[3], *bo[3];
  for (int l = 0; l < 3; ++l) {
    Wl[l] = (const float*)d_in[4 + 7 * l];
    bl[l] = (const float*)d_in[5 + 7 * l];
    Wr[l] = (const float*)d_in[6 + 7 * l];
    br[l] = (const float*)d_in[7 + 7 * l];
    We[l] = (const float*)d_in[8 + 7 * l];
    att[l] = (const float*)d_in[9 + 7 * l];
    bo[l] = (const float*)d_in[10 + 7 * l];
  }
  const float* lng[2] = {(const float*)d_in[25], (const float*)d_in[27]};
  const float* lnb[2] = {(const float*)d_in[26], (const float*)d_in[28]};
  const float* pw1 = (const float*)d_in[29];
  const float* pb1 = (const float*)d_in[30];
  const float* pw2 = (const float*)d_in[31];
  const float* pb2 = (const float*)d_in[32];
  const float* pw3 = (const float*)d_in[33];
  const float* pb3 = (const float*)d_in[34];
  const float* pw4 = (const float*)d_in[35];
  const float* pb4 = (const float*)d_in[36];

  char* base = (char*)d_ws;
  size_t cur = 0;
  auto carve = [&](size_t bytes) -> char* {
    char* p = base + cur;
    cur += (bytes + 255) & ~(size_t)255;
    return p;
  };
  unsigned short* xlb = (unsigned short*)carve((size_t)N * 128 * 2);
  unsigned short* xrb = (unsigned short*)carve((size_t)N * 128 * 2);
  unsigned short* xb = (unsigned short*)carve((size_t)N * 128 * 2);  // bf16 activations
  unsigned short* Wb = (unsigned short*)carve((size_t)6 * 16384 * 2);
  float4* e4 = (float4*)carve((size_t)(EP + 8) * 16);  // +8 pad records
  float4* staged = (float4*)carve((size_t)NBUK * BCAP * 16);
  int* offs = (int*)carve((size_t)(N + 1) * 4);
  int* gcnt = (int*)carve((size_t)NBUK * 4);
  int* bukStart = (int*)carve((size_t)(NBUK + 1) * 4);
  float* scoreTab = (float*)carve((size_t)3 * 512 * 4);
  float* pooled = (float*)carve((size_t)G * 128 * 4);

  float* emb_out = (float*)d_out;
  float* mlp_out = (float*)d_out + (size_t)N * 128;

  hipMemsetAsync(gcnt, 0, (size_t)NBUK * 4, stream);
  hipMemsetAsync(pooled, 0, (size_t)G * 128 * 4, stream);

  k_binA<<<(E + CHUNK - 1) / CHUNK, 256, 0, stream>>>(ei, ea, gcnt, staged, E, NBUK);
  k_bscan<<<1, 256, 0, stream>>>(gcnt, bukStart, offs, e4, N, NBUK, EP);
  k_binB<<<NBUK, 256, 0, stream>>>(staged, gcnt, bukStart, e4, offs, N);

  k_convx<<<(N * 128 / 4 + 255) / 256, 256, 0, stream>>>(x_in, xb, N * 128);
  {
    dim3 g(64, 6);
    k_convW<<<g, 256, 0, stream>>>(Wl[0], Wr[0], Wl[1], Wr[1], Wl[2], Wr[2], Wb);
  }
  k_pack<<<3, 16, 0, stream>>>(We[0], att[0], We[1], att[1], We[2], att[2], scoreTab);

  for (int l = 0; l < 3; ++l) {
    dim3 ggrid((N + 63) / 64, 2);
    k_gemm_mfma<<<ggrid, 256, 0, stream>>>(xb, Wb + (size_t)l * 32768, bl[l], br[l], xlb, xrb, N);
    int last = (l == 2) ? 1 : 0;
    const float* g = last ? bo[l] : lng[l];
    const float* b = last ? bo[l] : lnb[l];
    k_agg<<<(N * 64 + 255) / 256, 256, 0, stream>>>(xlb, xrb, e4, offs,
                                                    scoreTab + (size_t)l * 512,
                                                    bo[l], g, b,
                                                    xb, emb_out, last, N);
  }

  k_pool<<<(N + 63) / 64, 256, 0, stream>>>(emb_out, batch, pooled, N);
  k_mlp<<<G, 64, 0, stream>>>(pooled, pw1, pb1, pw2, pb2, pw3, pb3, pw4, pb4, mlp_out);
}

// Round 5
// 505.788 us; speedup vs baseline: 1.2032x; 1.2032x over previous
//
#include <hip/hip_runtime.h>
#include <math.h>

// ---------------------------------------------------------------------------
// GATv2 x3 + LN + graph max-pool + MLP.
// Round 14: k_agg REVERTED to R11 (proven best: 61.0us). R13's 4-edge
// re-decomposition regressed (96us: 4-iter loops -> latency cover lost).
// Non-agg restructuring instead:
//  (a) k_convx ELIMINATED: layer-0 GEMM reads f32 x directly, converts
//      in-register with identical RNE f2bf (bit-identical outputs).
//  (b) k_gemm merged: one kernel computes xl AND xr (xb tile loaded once,
//      64 MFMA/wave); GEMM dispatches 6 -> 3.
//  (c) prologue packed: {binA | convW | pack} one dispatch via blockIdx
//      role split (independent work co-schedules).
// Launches 16 -> 10 (+2 memsets).
// ---------------------------------------------------------------------------

#define LN_EPS 1e-5f
#define LOG2E 1.44269504088896340736f
#define CHUNK 4096
#define BCAP 8192  // records per staging bucket (avg 4096)

typedef short bf16x8 __attribute__((ext_vector_type(8)));
typedef float f32x4 __attribute__((ext_vector_type(4)));
typedef float f32x2 __attribute__((ext_vector_type(2)));

static __device__ __forceinline__ unsigned short f2bf(float f) {
  unsigned int u = __float_as_uint(f);
  u += 0x7fffu + ((u >> 16) & 1u);  // RNE
  return (unsigned short)(u >> 16);
}

// sum+broadcast over each 8-lane group: quad xor1, quad xor2, row_half_mirror
static __device__ __forceinline__ float dpp_sum8(float v) {
  int x;
  x = __builtin_amdgcn_update_dpp(0, __float_as_int(v), 0x0B1, 0xf, 0xf, true);  // quad_perm 1,0,3,2
  v += __int_as_float(x);
  x = __builtin_amdgcn_update_dpp(0, __float_as_int(v), 0x04E, 0xf, 0xf, true);  // quad_perm 2,3,0,1
  v += __int_as_float(x);
  x = __builtin_amdgcn_update_dpp(0, __float_as_int(v), 0x141, 0xf, 0xf, true);  // row_half_mirror
  v += __int_as_float(x);
  return v;
}

// ---------------- packed prologue: {binA | convW | pack} ----------------

__global__ __launch_bounds__(256) void k_pre(
    const int* __restrict__ ei, const float* __restrict__ ea,
    int* __restrict__ gcnt, float4* __restrict__ staged, int E, int nbuk, int nbinA,
    const float* __restrict__ w0, const float* __restrict__ w1,
    const float* __restrict__ w2, const float* __restrict__ w3,
    const float* __restrict__ w4, const float* __restrict__ w5,
    unsigned short* __restrict__ Wb,
    const float* __restrict__ We0, const float* __restrict__ att0,
    const float* __restrict__ We1, const float* __restrict__ att1,
    const float* __restrict__ We2, const float* __restrict__ att2,
    float* __restrict__ tab) {
  __shared__ int hist[256];
  __shared__ int basebuf[256];
  int b = blockIdx.x;
  int t = threadIdx.x;

  if (b < nbinA) {
    // ---- binA: histogram edges into 256-node buckets, stage records ----
    int e0 = b * CHUNK;
    hist[t] = 0;
    __syncthreads();
#pragma unroll
    for (int i = 0; i < CHUNK / 256; ++i) {
      int e = e0 + i * 256 + t;
      if (e < E) atomicAdd(&hist[ei[E + e] >> 8], 1);
    }
    __syncthreads();
    int h = hist[t];
    if (t < nbuk && h > 0) basebuf[t] = t * BCAP + atomicAdd(&gcnt[t], h);
    hist[t] = 0;
    __syncthreads();
#pragma unroll
    for (int i = 0; i < CHUNK / 256; ++i) {
      int e = e0 + i * 256 + t;
      if (e < E) {
        int s = ei[e];
        int d = ei[E + e];
        int bk = d >> 8;
        int r = atomicAdd(&hist[bk], 1);
        float4 rec;
        rec.x = ea[e * 3 + 0];
        rec.y = ea[e * 3 + 1];
        rec.z = ea[e * 3 + 2];
        rec.w = __int_as_float(s | (d << 16));
        staged[basebuf[bk] + r] = rec;
      }
    }
  } else if (b < nbinA + 384) {
    // ---- convW: 6 x 16384 f32 -> bf16 ----
    int bb = b - nbinA;
    const float* srcs[6] = {w0, w1, w2, w3, w4, w5};
    int mtx = bb >> 6;
    int i = (bb & 63) * 256 + t;
    Wb[(size_t)mtx * 16384 + i] = f2bf(srcs[mtx][i]);
  } else {
    // ---- pack: per-layer, per-lane score params ----
    if (t < 96) {
      int l = t >> 5;
      int sl = t & 31;
      const float* We = (l == 0) ? We0 : ((l == 1) ? We1 : We2);
      const float* att = (l == 0) ? att0 : ((l == 1) ? att1 : att2);
      float* o = tab + (size_t)l * 512 + sl * 16;
#pragma unroll
      for (int j = 0; j < 4; ++j) {
        o[j] = We[(sl * 4 + j) * 3 + 0];
        o[4 + j] = We[(sl * 4 + j) * 3 + 1];
        o[8 + j] = We[(sl * 4 + j) * 3 + 2];
        o[12 + j] = att[sl * 4 + j] * LOG2E;
      }
    }
  }
}

__global__ void k_bscan(const int* __restrict__ gcnt, int* __restrict__ bukStart,
                        int* __restrict__ offs, float4* __restrict__ e4,
                        int N, int nbuk, int EP) {
  __shared__ int sh[256];
  int t = threadIdx.x;
  int nodes = (t < nbuk) ? min(256, N - t * 256) : 0;
  int v = (t < nbuk) ? gcnt[t] + nodes : 0;
  sh[t] = v;
  __syncthreads();
  for (int d = 1; d < 256; d <<= 1) {
    int add = (t >= d) ? sh[t - d] : 0;
    __syncthreads();
    sh[t] += add;
    __syncthreads();
  }
  if (t < nbuk) bukStart[t] = sh[t] - v;
  if (t == 0) offs[N] = EP;
  // pad records past EP: valid gather offset (row 0), finite attrs.
  if (t < 8) {
    float4 r;
    r.x = 0.f; r.y = 0.f; r.z = 0.f;
    r.w = __int_as_float(0);
    e4[EP + t] = r;
  }
}

__global__ __launch_bounds__(256) void k_binB(const float4* __restrict__ staged,
                                              const int* __restrict__ gcnt,
                                              const int* __restrict__ bukStart,
                                              float4* __restrict__ e4,
                                              int* __restrict__ offs, int N) {
  __shared__ int hist[256], cur[256], begS[256], sh[256];
  int t = threadIdx.x;
  int b = blockIdx.x;
  int n0 = b * 256;
  int nn = min(256, N - n0);
  int m = gcnt[b];
  size_t sbase = (size_t)b * BCAP;

  hist[t] = 0;
  __syncthreads();
  for (int p = t; p < m; p += 256) {
    unsigned int u = (unsigned int)__float_as_int(staged[sbase + p].w);
    atomicAdd(&hist[(int)(u >> 16) - n0], 1);
  }
  __syncthreads();
  int v = (t < nn) ? hist[t] + 1 : 0;
  sh[t] = v;
  __syncthreads();
  for (int d = 1; d < 256; d <<= 1) {
    int add = (t >= d) ? sh[t - d] : 0;
    __syncthreads();
    sh[t] += add;
    __syncthreads();
  }
  if (t < nn) {
    int base = bukStart[b] + sh[t] - v;
    cur[t] = base;
    begS[t] = base;
    offs[n0 + t] = base;
  }
  __syncthreads();
  for (int p = t; p < m; p += 256) {
    float4 rec = staged[sbase + p];
    unsigned int u = (unsigned int)__float_as_int(rec.w);
    int pos = atomicAdd(&cur[(int)(u >> 16) - n0], 1);
    rec.w = __int_as_float((int)(u & 0xffffu) * 256);
    e4[pos] = rec;
  }
  __syncthreads();
  if (t < nn) {
    int beg = begS[t], last = cur[t];  // cur == self-loop slot after placement
    float s0 = 0.f, s1 = 0.f, s2 = 0.f;
    for (int p = beg; p < last; ++p) {
      float4 r = e4[p];
      s0 += r.x;
      s1 += r.y;
      s2 += r.z;
    }
    float invc = 1.0f / fmaxf((float)(last - beg), 1.0f);
    float4 r;
    r.x = s0 * invc;
    r.y = s1 * invc;
    r.z = s2 * invc;
    r.w = __int_as_float((n0 + t) * 256);
    e4[last] = r;
  }
}

// ---------------- merged MFMA GEMM: xl AND xr in one pass ----------------
// A=W rows (channel jt*16+m), B=x rows (node row0+m); D row=channel q*4+r,
// col=node m -> lane holds 4 contiguous channels -> uint2 packed stores.
// F32IN: layer-0 reads f32 x and converts in-register (RNE, == old k_convx).
template <bool F32IN>
__global__ __launch_bounds__(256) void k_gemm_fused(const float* __restrict__ xf,
                                                    const unsigned short* __restrict__ xb,
                                                    const unsigned short* __restrict__ Wb,
                                                    const float* __restrict__ bl,
                                                    const float* __restrict__ br,
                                                    unsigned short* __restrict__ xlb,
                                                    unsigned short* __restrict__ xrb, int N) {
  int wave = threadIdx.x >> 6;
  int lane = threadIdx.x & 63;
  const unsigned short* WL = Wb;
  const unsigned short* WR = Wb + 16384;

  int row0 = (blockIdx.x * 4 + wave) * 16;
  if (row0 >= N) return;
  int m = lane & 15;
  int q = lane >> 4;

  int brow = row0 + m;
  if (brow >= N) brow = N - 1;

  bf16x8 bfrag[4];
  if constexpr (F32IN) {
    const float* xrow = xf + (size_t)brow * 128 + q * 8;
#pragma unroll
    for (int kt = 0; kt < 4; ++kt) {
      float4 u0 = *(const float4*)(xrow + kt * 32);
      float4 u1 = *(const float4*)(xrow + kt * 32 + 4);
      bf16x8 f;
      f[0] = (short)f2bf(u0.x); f[1] = (short)f2bf(u0.y);
      f[2] = (short)f2bf(u0.z); f[3] = (short)f2bf(u0.w);
      f[4] = (short)f2bf(u1.x); f[5] = (short)f2bf(u1.y);
      f[6] = (short)f2bf(u1.z); f[7] = (short)f2bf(u1.w);
      bfrag[kt] = f;
    }
  } else {
    const unsigned short* xrow = xb + (size_t)brow * 128 + q * 8;
#pragma unroll
    for (int kt = 0; kt < 4; ++kt) bfrag[kt] = *(const bf16x8*)(xrow + kt * 32);
  }

  f32x4 accL[8], accR[8];
#pragma unroll
  for (int jt = 0; jt < 8; ++jt) {
    accL[jt] = (f32x4){0.f, 0.f, 0.f, 0.f};
    accR[jt] = (f32x4){0.f, 0.f, 0.f, 0.f};
  }

  const unsigned short* wl = WL + (size_t)m * 128 + q * 8;
  const unsigned short* wr = WR + (size_t)m * 128 + q * 8;
#pragma unroll
  for (int kt = 0; kt < 4; ++kt) {
#pragma unroll
    for (int jt = 0; jt < 8; ++jt) {
      bf16x8 aL = *(const bf16x8*)(wl + (size_t)jt * 2048 + kt * 32);
      accL[jt] = __builtin_amdgcn_mfma_f32_16x16x32_bf16(aL, bfrag[kt], accL[jt], 0, 0, 0);
      bf16x8 aR = *(const bf16x8*)(wr + (size_t)jt * 2048 + kt * 32);
      accR[jt] = __builtin_amdgcn_mfma_f32_16x16x32_bf16(aR, bfrag[kt], accR[jt], 0, 0, 0);
    }
  }

  int node = row0 + m;
  if (node < N) {
    unsigned short* ol = xlb + (size_t)node * 128 + q * 4;
    unsigned short* orr = xrb + (size_t)node * 128 + q * 4;
#pragma unroll
    for (int jt = 0; jt < 8; ++jt) {
      float4 bsL = *(const float4*)&bl[jt * 16 + q * 4];
      uint2 pL;
      pL.x = (unsigned int)f2bf(accL[jt][0] + bsL.x) | ((unsigned int)f2bf(accL[jt][1] + bsL.y) << 16);
      pL.y = (unsigned int)f2bf(accL[jt][2] + bsL.z) | ((unsigned int)f2bf(accL[jt][3] + bsL.w) << 16);
      *(uint2*)(ol + jt * 16) = pL;
      float4 bsR = *(const float4*)&br[jt * 16 + q * 4];
      uint2 pR;
      pR.x = (unsigned int)f2bf(accR[jt][0] + bsR.x) | ((unsigned int)f2bf(accR[jt][1] + bsR.y) << 16);
      pR.y = (unsigned int)f2bf(accR[jt][2] + bsR.z) | ((unsigned int)f2bf(accR[jt][3] + bsR.w) << 16);
      *(uint2*)(orr + jt * 16) = pR;
    }
  }
}

// ---------------- fused: score + softmax(exp2) + weighted agg + epilogue ----------------
// one wave per node; lanes 0-31 = edge p, lanes 32-63 = edge p+1 (same node);
// each lane owns 4 channels c = (lane&31)*4; head group = 8 lanes.
// (R11 version verbatim -- proven best.)
__global__ __launch_bounds__(256) void k_agg(const unsigned short* __restrict__ xlb,
                                             const unsigned short* __restrict__ xrb,
                                             const float4* __restrict__ e4,
                                             const int* __restrict__ offs,
                                             const float* __restrict__ scoreTab,
                                             const float* __restrict__ bo,
                                             const float* __restrict__ lng, const float* __restrict__ lnb,
                                             unsigned short* __restrict__ xnext_bf,
                                             float* __restrict__ emb, int last, int N) {
  int w = (blockIdx.x * blockDim.x + threadIdx.x) >> 6;
  if (w >= N) return;
  int lane = threadIdx.x & 63;
  int half = lane >> 5;
  int sl = lane & 31;
  int c = sl * 4;
  unsigned int c2 = (unsigned int)(c * 2);  // byte offset into bf16 row
  int beg = offs[w], end = offs[w + 1];
  int cnt = end - beg;

  // packed per-lane params as float2 halves (channels 01 / 23)
  f32x2 xr01, xr23, wea01, wea23, web01, web23, wec01, wec23, at01, at23;
  {
    const float4* tp = (const float4*)(scoreTab + (size_t)sl * 16);
    float4 pa = tp[0], pb = tp[1], pc = tp[2], pt = tp[3];
    wea01[0] = pa.x; wea01[1] = pa.y; wea23[0] = pa.z; wea23[1] = pa.w;
    web01[0] = pb.x; web01[1] = pb.y; web23[0] = pb.z; web23[1] = pb.w;
    wec01[0] = pc.x; wec01[1] = pc.y; wec23[0] = pc.z; wec23[1] = pc.w;
    at01[0] = pt.x; at01[1] = pt.y; at23[0] = pt.z; at23[1] = pt.w;
    uint2 vr = *(const uint2*)&xrb[(size_t)w * 128 + c];
    xr01[0] = __uint_as_float(vr.x << 16);
    xr01[1] = __uint_as_float(vr.x & 0xffff0000u);
    xr23[0] = __uint_as_float(vr.y << 16);
    xr23[1] = __uint_as_float(vr.y & 0xffff0000u);
  }

  const char* e4B = (const char*)e4;
  const char* xlB = (const char*)xlb;

  float l = 0.f;
  f32x2 acc01 = {0.f, 0.f}, acc23 = {0.f, 0.f};

  unsigned int lastoff = (unsigned int)(end - 1) << 4;
  int T = (cnt + 1) >> 1;  // pair iterations

  // ---- pipeline prologue: records for pairs 0..2, gathers for pairs 0..1 ----
  unsigned int o0 = (unsigned int)(beg + half) << 4;
  if (o0 > lastoff) o0 = lastoff;  // cnt==1, half 1 clamps
  unsigned int o1 = o0 + 32u;
  if (o1 > lastoff) o1 = lastoff;
  unsigned int o2 = o1 + 32u;
  if (o2 > lastoff) o2 = lastoff;
  float4 e0 = *(const float4*)(e4B + o0);
  float4 e1 = *(const float4*)(e4B + o1);
  float4 e2 = *(const float4*)(e4B + o2);
  uint2 g0 = *(const uint2*)(xlB + ((unsigned int)__float_as_int(e0.w) + c2));
  uint2 g1 = *(const uint2*)(xlB + ((unsigned int)__float_as_int(e1.w) + c2));
  unsigned int offP = o2;

  // one edge: unpack gather, score (packed f32), exp2, accumulate.
  auto compute = [&](const float4& e, uint2 v, bool valid) {
    f32x2 xl01, xl23;
    xl01[0] = __uint_as_float(v.x << 16);
    xl01[1] = __uint_as_float(v.x & 0xffff0000u);
    xl23[0] = __uint_as_float(v.y << 16);
    xl23[1] = __uint_as_float(v.y & 0xffff0000u);
    f32x2 ex = {e.x, e.x}, ey = {e.y, e.y}, ez = {e.z, e.z};
    f32x2 t01 = __builtin_elementwise_fma(wea01, ex,
                  __builtin_elementwise_fma(web01, ey,
                    __builtin_elementwise_fma(wec01, ez, xr01 + xl01)));
    f32x2 t23 = __builtin_elementwise_fma(wea23, ex,
                  __builtin_elementwise_fma(web23, ey,
                    __builtin_elementwise_fma(wec23, ez, xr23 + xl23)));
    t01 = __builtin_elementwise_max(t01, t01 * 0.2f);
    t23 = __builtin_elementwise_max(t23, t23 * 0.2f);
    f32x2 d2 = __builtin_elementwise_fma(t01, at01, t23 * at23);
    float s = d2[0] + d2[1];
    float wgt = __builtin_amdgcn_exp2f(dpp_sum8(s));
    if (!valid) wgt = 0.f;
    l += wgt;
    f32x2 w2 = {wgt, wgt};
    acc01 = __builtin_elementwise_fma(xl01, w2, acc01);
    acc23 = __builtin_elementwise_fma(xl23, w2, acc23);
  };

  // ---- steady state: record(i+3), gather(i+2), compute(i) ----
#pragma unroll 2
  for (int it = 0; it < T - 3; ++it) {
    unsigned int o3 = offP + 32u;
    if (o3 > lastoff) o3 = lastoff;
    float4 e3 = *(const float4*)(e4B + o3);
    uint2 g2 = *(const uint2*)(xlB + ((unsigned int)__float_as_int(e2.w) + c2));
    compute(e0, g0, true);
    e0 = e1; e1 = e2; e2 = e3;
    g0 = g1; g1 = g2;
    offP = o3;
  }
  if (T >= 3) {  // pair T-3: issue last gather, compute
    uint2 g2 = *(const uint2*)(xlB + ((unsigned int)__float_as_int(e2.w) + c2));
    compute(e0, g0, true);
    e0 = e1; e1 = e2;
    g0 = g1; g1 = g2;
  }
  if (T >= 2) {  // pair T-2 (always fully valid)
    compute(e0, g0, true);
    e0 = e1;
    g0 = g1;
  }
  {  // pair T-1 (masked: odd cnt leaves half==1 invalid)
    int idx = 2 * (T - 1) + half;
    compute(e0, g0, idx < cnt);
  }

  // combine halves
  l += __shfl_xor(l, 32);
  float a0 = acc01[0]; a0 += __shfl_xor(a0, 32);
  float a1 = acc01[1]; a1 += __shfl_xor(a1, 32);
  float a2 = acc23[0]; a2 += __shfl_xor(a2, 32);
  float a3 = acc23[1]; a3 += __shfl_xor(a3, 32);

  float inv = 1.0f / l;
  f32x4 o4;
  const float4 bo4 = *(const float4*)&bo[c];
  o4[0] = a0 * inv + bo4.x;
  o4[1] = a1 * inv + bo4.y;
  o4[2] = a2 * inv + bo4.z;
  o4[3] = a3 * inv + bo4.w;

  if (last) {
    if (half == 0) {
      float4 st = {o4[0], o4[1], o4[2], o4[3]};
      *(float4*)&emb[(size_t)w * 128 + c] = st;
    }
  } else {
    f32x4 r;
    r[0] = fmaxf(o4[0], 0.f);
    r[1] = fmaxf(o4[1], 0.f);
    r[2] = fmaxf(o4[2], 0.f);
    r[3] = fmaxf(o4[3], 0.f);
    float s = r[0] + r[1] + r[2] + r[3];
    s += __shfl_xor(s, 1);
    s += __shfl_xor(s, 2);
    s += __shfl_xor(s, 4);
    s += __shfl_xor(s, 8);
    s += __shfl_xor(s, 16);
    float mu = s * 0.0078125f;  // /128
    f32x4 d;
    d[0] = r[0] - mu;
    d[1] = r[1] - mu;
    d[2] = r[2] - mu;
    d[3] = r[3] - mu;
    float v2 = d[0] * d[0] + d[1] * d[1] + d[2] * d[2] + d[3] * d[3];
    v2 += __shfl_xor(v2, 1);
    v2 += __shfl_xor(v2, 2);
    v2 += __shfl_xor(v2, 4);
    v2 += __shfl_xor(v2, 8);
    v2 += __shfl_xor(v2, 16);
    float var = v2 * 0.0078125f;
    float rstd = rsqrtf(var + LN_EPS);
    if (half == 0) {
      const float4 g4 = *(const float4*)&lng[c];
      const float4 b4 = *(const float4*)&lnb[c];
      float o0 = d[0] * rstd * g4.x + b4.x;
      float o1 = d[1] * rstd * g4.y + b4.y;
      float o2 = d[2] * rstd * g4.z + b4.z;
      float o3 = d[3] * rstd * g4.w + b4.w;
      uint2 pack;
      pack.x = (unsigned int)f2bf(o0) | ((unsigned int)f2bf(o1) << 16);
      pack.y = (unsigned int)f2bf(o2) | ((unsigned int)f2bf(o3) << 16);
      *(uint2*)&xnext_bf[(size_t)w * 128 + c] = pack;
    }
  }
}

// ---------------- graph max-pool (relu implicit: atomicMax vs 0-init) ----------------
__global__ void k_pool(const float* __restrict__ emb, const int* __restrict__ batch,
                       float* __restrict__ pooled, int N) {
  int c = threadIdx.x & 127;
  int half = threadIdx.x >> 7;
  int base = blockIdx.x * 64 + half;
  int limit = min(blockIdx.x * 64 + 64, N);
  float cur = 0.f;
  int curg = -1;
  for (int n = base; n < limit; n += 2) {
    int g = batch[n];
    if (g != curg) {
      if (curg >= 0) atomicMax((unsigned int*)&pooled[curg * 128 + c], __float_as_uint(cur));
      curg = g;
      cur = 0.f;
    }
    cur = fmaxf(cur, emb[(size_t)n * 128 + c]);
  }
  if (curg >= 0) atomicMax((unsigned int*)&pooled[curg * 128 + c], __float_as_uint(cur));
}

// ---------------- MLP: 128 -> 32 -> 32 -> 32 -> 1 ----------------
__global__ void k_mlp(const float* __restrict__ pooled,
                      const float* __restrict__ pw1, const float* __restrict__ pb1,
                      const float* __restrict__ pw2, const float* __restrict__ pb2,
                      const float* __restrict__ pw3, const float* __restrict__ pb3,
                      const float* __restrict__ pw4, const float* __restrict__ pb4,
                      float* __restrict__ out) {
  int g = blockIdx.x;
  int t = threadIdx.x;  // 64 threads
  __shared__ float buf1[32], buf2[32];
  if (t < 32) {
    float acc = pb1[t];
    for (int k = 0; k < 128; ++k) acc += pw1[t * 128 + k] * pooled[g * 128 + k];
    buf1[t] = fmaxf(acc, 0.f);
  }
  __syncthreads();
  if (t < 32) {
    float acc = pb2[t];
    for (int k = 0; k < 32; ++k) acc += pw2[t * 32 + k] * buf1[k];
    buf2[t] = fmaxf(acc, 0.f);
  }
  __syncthreads();
  if (t < 32) {
    float acc = pb3[t];
    for (int k = 0; k < 32; ++k) acc += pw3[t * 32 + k] * buf2[k];
    buf1[t] = fmaxf(acc, 0.f);
  }
  __syncthreads();
  if (t == 0) {
    float acc = pb4[0];
    for (int k = 0; k < 32; ++k) acc += pw4[k] * buf1[k];
    out[g] = acc;
  }
}

// ---------------------------------------------------------------------------

extern "C" void kernel_launch(void* const* d_in, const int* in_sizes, int n_in,
                              void* d_out, int out_size, void* d_ws, size_t ws_size,
                              hipStream_t stream) {
  const float* x_in = (const float*)d_in[0];
  const int* ei = (const int*)d_in[1];
  const int* batch = (const int*)d_in[2];
  const float* ea = (const float*)d_in[3];

  const int N = in_sizes[0] / 128;
  const int E = in_sizes[1] / 2;
  const int EP = E + N;
  const int G = out_size - N * 128;
  const int NBUK = (N + 255) / 256;
  const int NBINA = (E + CHUNK - 1) / CHUNK;

  const float *Wl[3], *bl[3], *Wr[3], *br[3], *We[3], *att[3], *bo[3];
  for (int l = 0; l < 3; ++l) {
    Wl[l] = (const float*)d_in[4 + 7 * l];
    bl[l] = (const float*)d_in[5 + 7 * l];
    Wr[l] = (const float*)d_in[6 + 7 * l];
    br[l] = (const float*)d_in[7 + 7 * l];
    We[l] = (const float*)d_in[8 + 7 * l];
    att[l] = (const float*)d_in[9 + 7 * l];
    bo[l] = (const float*)d_in[10 + 7 * l];
  }
  const float* lng[2] = {(const float*)d_in[25], (const float*)d_in[27]};
  const float* lnb[2] = {(const float*)d_in[26], (const float*)d_in[28]};
  const float* pw1 = (const float*)d_in[29];
  const float* pb1 = (const float*)d_in[30];
  const float* pw2 = (const float*)d_in[31];
  const float* pb2 = (const float*)d_in[32];
  const float* pw3 = (const float*)d_in[33];
  const float* pb3 = (const float*)d_in[34];
  const float* pw4 = (const float*)d_in[35];
  const float* pb4 = (const float*)d_in[36];

  char* base = (char*)d_ws;
  size_t cur = 0;
  auto carve = [&](size_t bytes) -> char* {
    char* p = base + cur;
    cur += (bytes + 255) & ~(size_t)255;
    return p;
  };
  unsigned short* xlb = (unsigned short*)carve((size_t)N * 128 * 2);
  unsigned short* xrb = (unsigned short*)carve((size_t)N * 128 * 2);
  unsigned short* xb = (unsigned short*)carve((size_t)N * 128 * 2);  // bf16 activations (layers 1,2)
  unsigned short* Wb = (unsigned short*)carve((size_t)6 * 16384 * 2);
  float4* e4 = (float4*)carve((size_t)(EP + 8) * 16);  // +8 pad records
  float4* staged = (float4*)carve((size_t)NBUK * BCAP * 16);
  int* offs = (int*)carve((size_t)(N + 1) * 4);
  int* gcnt = (int*)carve((size_t)NBUK * 4);
  int* bukStart = (int*)carve((size_t)(NBUK + 1) * 4);
  float* scoreTab = (float*)carve((size_t)3 * 512 * 4);
  float* pooled = (float*)carve((size_t)G * 128 * 4);

  float* emb_out = (float*)d_out;
  float* mlp_out = (float*)d_out + (size_t)N * 128;

  hipMemsetAsync(gcnt, 0, (size_t)NBUK * 4, stream);
  hipMemsetAsync(pooled, 0, (size_t)G * 128 * 4, stream);

  // packed prologue: binA blocks + convW blocks + 1 pack block
  k_pre<<<NBINA + 384 + 1, 256, 0, stream>>>(ei, ea, gcnt, staged, E, NBUK, NBINA,
                                             Wl[0], Wr[0], Wl[1], Wr[1], Wl[2], Wr[2], Wb,
                                             We[0], att[0], We[1], att[1], We[2], att[2],
                                             scoreTab);
  k_bscan<<<1, 256, 0, stream>>>(gcnt, bukStart, offs, e4, N, NBUK, EP);
  k_binB<<<NBUK, 256, 0, stream>>>(staged, gcnt, bukStart, e4, offs, N);

  for (int l = 0; l < 3; ++l) {
    dim3 ggrid((N + 63) / 64);
    if (l == 0) {
      k_gemm_fused<true><<<ggrid, 256, 0, stream>>>(x_in, xb, Wb, bl[0], br[0], xlb, xrb, N);
    } else {
      k_gemm_fused<false><<<ggrid, 256, 0, stream>>>(nullptr, xb, Wb + (size_t)l * 32768,
                                                     bl[l], br[l], xlb, xrb, N);
    }
    int last = (l == 2) ? 1 : 0;
    const float* g = last ? bo[l] : lng[l];
    const float* b = last ? bo[l] : lnb[l];
    k_agg<<<(N * 64 + 255) / 256, 256, 0, stream>>>(xlb, xrb, e4, offs,
                                                    scoreTab + (size_t)l * 512,
                                                    bo[l], g, b,
                                                    xb, emb_out, last, N);
  }

  k_pool<<<(N + 63) / 64, 256, 0, stream>>>(emb_out, batch, pooled, N);
  k_mlp<<<G, 64, 0, stream>>>(pooled, pw1, pb1, pw2, pb2, pw3, pb3, pw4, pb4, mlp_out);
}

// Round 6
// 470.831 us; speedup vs baseline: 1.2925x; 1.0742x over previous
//
#include <hip/hip_runtime.h>
#include <math.h>

// ---------------------------------------------------------------------------
// GATv2 x3 + LN + graph max-pool + MLP.
// Round 15: request-rate fixes in the second tier (k_agg untouched = R11).
//  (a) W packed into MFMA-fragment order (k_pre): gemm A-loads coalesced
//      (base + lane*16B, 1KB/instr vs 64 scattered 16B reqs).
//  (b) xb (inter-layer activations) packed into fragment order by k_agg's
//      epilogue (same instruction count, permuted addresses): gemm B-loads
//      coalesced.
//  (c) gemm stores via per-wave LDS transpose -> 4x dwordx4 coalesced
//      stores per matrix (vs 16 scattered 8B stores).
//  (d) k_bscan folded into k_binB (per-block local prefix over gcnt);
//      self-loop attr means via LDS atomics in the placement pass (kills
//      the 13MB uncoalesced e4 re-scan + one dispatch).
// ---------------------------------------------------------------------------

#define LN_EPS 1e-5f
#define LOG2E 1.44269504088896340736f
#define CHUNK 4096
#define BCAP 8192  // records per staging bucket (avg 4096)

typedef short bf16x8 __attribute__((ext_vector_type(8)));
typedef float f32x4 __attribute__((ext_vector_type(4)));
typedef float f32x2 __attribute__((ext_vector_type(2)));

static __device__ __forceinline__ unsigned short f2bf(float f) {
  unsigned int u = __float_as_uint(f);
  u += 0x7fffu + ((u >> 16) & 1u);  // RNE
  return (unsigned short)(u >> 16);
}

// sum+broadcast over each 8-lane group: quad xor1, quad xor2, row_half_mirror
static __device__ __forceinline__ float dpp_sum8(float v) {
  int x;
  x = __builtin_amdgcn_update_dpp(0, __float_as_int(v), 0x0B1, 0xf, 0xf, true);  // quad_perm 1,0,3,2
  v += __int_as_float(x);
  x = __builtin_amdgcn_update_dpp(0, __float_as_int(v), 0x04E, 0xf, 0xf, true);  // quad_perm 2,3,0,1
  v += __int_as_float(x);
  x = __builtin_amdgcn_update_dpp(0, __float_as_int(v), 0x141, 0xf, 0xf, true);  // row_half_mirror
  v += __int_as_float(x);
  return v;
}

// ---------------- packed prologue: {binA | convW(packed) | pack} ----------------
// W fragment layout per matrix (16384 ushorts):
//   chunk c in [0,2048): lane=c&63, kt=(c>>6)&3, jt=c>>8
//   Wp[c*8+j] = W[(jt*16 + (lane&15))*128 + kt*32 + (lane>>4)*8 + j]
__global__ __launch_bounds__(256) void k_pre(
    const int* __restrict__ ei, const float* __restrict__ ea,
    int* __restrict__ gcnt, float4* __restrict__ staged, int E, int nbuk, int nbinA,
    const float* __restrict__ w0, const float* __restrict__ w1,
    const float* __restrict__ w2, const float* __restrict__ w3,
    const float* __restrict__ w4, const float* __restrict__ w5,
    unsigned short* __restrict__ Wb,
    const float* __restrict__ We0, const float* __restrict__ att0,
    const float* __restrict__ We1, const float* __restrict__ att1,
    const float* __restrict__ We2, const float* __restrict__ att2,
    float* __restrict__ tab) {
  __shared__ int hist[256];
  __shared__ int basebuf[256];
  int b = blockIdx.x;
  int t = threadIdx.x;

  if (b < nbinA) {
    // ---- binA: histogram edges into 256-node buckets, stage records ----
    int e0 = b * CHUNK;
    hist[t] = 0;
    __syncthreads();
#pragma unroll
    for (int i = 0; i < CHUNK / 256; ++i) {
      int e = e0 + i * 256 + t;
      if (e < E) atomicAdd(&hist[ei[E + e] >> 8], 1);
    }
    __syncthreads();
    int h = hist[t];
    if (t < nbuk && h > 0) basebuf[t] = t * BCAP + atomicAdd(&gcnt[t], h);
    hist[t] = 0;
    __syncthreads();
#pragma unroll
    for (int i = 0; i < CHUNK / 256; ++i) {
      int e = e0 + i * 256 + t;
      if (e < E) {
        int s = ei[e];
        int d = ei[E + e];
        int bk = d >> 8;
        int r = atomicAdd(&hist[bk], 1);
        float4 rec;
        rec.x = ea[e * 3 + 0];
        rec.y = ea[e * 3 + 1];
        rec.z = ea[e * 3 + 2];
        rec.w = __int_as_float(s | (d << 16));
        staged[basebuf[bk] + r] = rec;
      }
    }
  } else if (b < nbinA + 48) {
    // ---- convW packed: 6 matrices x 8 blocks; thread does one 8-elem chunk ----
    int bb = b - nbinA;
    const float* srcs[6] = {w0, w1, w2, w3, w4, w5};
    int mtx = bb >> 3;
    int c = (bb & 7) * 256 + t;  // chunk in [0,2048)
    int lane = c & 63;
    int kt = (c >> 6) & 3;
    int jt = c >> 8;
    const float* s = srcs[mtx] + (size_t)(jt * 16 + (lane & 15)) * 128 + kt * 32 + (lane >> 4) * 8;
    unsigned short* d = Wb + (size_t)mtx * 16384 + (size_t)c * 8;
#pragma unroll
    for (int j = 0; j < 8; ++j) d[j] = f2bf(s[j]);
  } else {
    // ---- pack: per-layer, per-lane score params ----
    if (t < 96) {
      int l = t >> 5;
      int sl = t & 31;
      const float* We = (l == 0) ? We0 : ((l == 1) ? We1 : We2);
      const float* att = (l == 0) ? att0 : ((l == 1) ? att1 : att2);
      float* o = tab + (size_t)l * 512 + sl * 16;
#pragma unroll
      for (int j = 0; j < 4; ++j) {
        o[j] = We[(sl * 4 + j) * 3 + 0];
        o[4 + j] = We[(sl * 4 + j) * 3 + 1];
        o[8 + j] = We[(sl * 4 + j) * 3 + 2];
        o[12 + j] = att[sl * 4 + j] * LOG2E;
      }
    }
  }
}

// ---------------- binB + folded bucket-prefix scan + LDS attr sums ----------------
__global__ __launch_bounds__(256) void k_binB(const float4* __restrict__ staged,
                                              const int* __restrict__ gcnt,
                                              float4* __restrict__ e4,
                                              int* __restrict__ offs, int N, int nbuk, int EP) {
  __shared__ int hist[256], cur[256], begS[256], sh[256];
  __shared__ float sX[256], sY[256], sZ[256];
  int t = threadIdx.x;
  int b = blockIdx.x;
  int n0 = b * 256;
  int nn = min(256, N - n0);
  int m = gcnt[b];
  size_t sbase = (size_t)b * BCAP;

  // ---- global bucket prefix (each block computes locally; removes k_bscan) ----
  {
    int nodes_t = (t < nbuk) ? min(256, N - t * 256) : 0;
    int v0 = (t < nbuk) ? gcnt[t] + nodes_t : 0;
    sh[t] = v0;
    __syncthreads();
    for (int d = 1; d < 256; d <<= 1) {
      int add = (t >= d) ? sh[t - d] : 0;
      __syncthreads();
      sh[t] += add;
      __syncthreads();
    }
  }
  int bukStart_b = (b == 0) ? 0 : sh[b - 1];
  if (b == 0) {
    if (t == 0) offs[N] = EP;
    if (t < 8) {  // pad records: valid gather offset (row 0), finite attrs
      float4 r;
      r.x = 0.f; r.y = 0.f; r.z = 0.f;
      r.w = __int_as_float(0);
      e4[EP + t] = r;
    }
  }
  __syncthreads();

  // ---- per-node histogram within bucket ----
  hist[t] = 0;
  sX[t] = 0.f; sY[t] = 0.f; sZ[t] = 0.f;
  __syncthreads();
  for (int p = t; p < m; p += 256) {
    unsigned int u = (unsigned int)__float_as_int(staged[sbase + p].w);
    atomicAdd(&hist[(int)(u >> 16) - n0], 1);
  }
  __syncthreads();
  int v = (t < nn) ? hist[t] + 1 : 0;
  sh[t] = v;
  __syncthreads();
  for (int d = 1; d < 256; d <<= 1) {
    int add = (t >= d) ? sh[t - d] : 0;
    __syncthreads();
    sh[t] += add;
    __syncthreads();
  }
  if (t < nn) {
    int base = bukStart_b + sh[t] - v;
    cur[t] = base;
    begS[t] = base;
    offs[n0 + t] = base;
  }
  __syncthreads();
  // ---- placement + attr sums (LDS atomics; replaces serial e4 re-scan) ----
  for (int p = t; p < m; p += 256) {
    float4 rec = staged[sbase + p];
    unsigned int u = (unsigned int)__float_as_int(rec.w);
    int d = (int)(u >> 16) - n0;
    int pos = atomicAdd(&cur[d], 1);
    atomicAdd(&sX[d], rec.x);
    atomicAdd(&sY[d], rec.y);
    atomicAdd(&sZ[d], rec.z);
    rec.w = __int_as_float((int)(u & 0xffffu) * 256);
    e4[pos] = rec;
  }
  __syncthreads();
  if (t < nn) {
    int beg = begS[t], last = cur[t];  // cur == self-loop slot after placement
    float invc = 1.0f / fmaxf((float)(last - beg), 1.0f);
    float4 r;
    r.x = sX[t] * invc;
    r.y = sY[t] * invc;
    r.z = sZ[t] * invc;
    r.w = __int_as_float((n0 + t) * 256);
    e4[last] = r;
  }
}

// ---------------- merged MFMA GEMM: xl AND xr in one pass ----------------
// A = W in fragment-packed layout (coalesced lane*16B loads). B = x:
//   layer 0 reads f32 x_in rows (+in-register RNE convert);
//   layers 1,2 read xpack (fragment-packed by k_agg's epilogue) coalesced.
// Stores via per-wave LDS transpose -> 4x dwordx4 coalesced per matrix.
template <bool F32IN>
__global__ __launch_bounds__(256) void k_gemm_fused(const float* __restrict__ xf,
                                                    const unsigned short* __restrict__ xpack,
                                                    const unsigned short* __restrict__ Wb,
                                                    const float* __restrict__ bl,
                                                    const float* __restrict__ br,
                                                    unsigned short* __restrict__ xlb,
                                                    unsigned short* __restrict__ xrb, int N) {
  __shared__ unsigned short sld[4][2048];  // per-wave 16 nodes x 128ch
  int wave = threadIdx.x >> 6;
  int lane = threadIdx.x & 63;
  const unsigned short* WL = Wb;
  const unsigned short* WR = Wb + 16384;

  int row0 = (blockIdx.x * 4 + wave) * 16;
  if (row0 >= N) return;
  int m = lane & 15;
  int q = lane >> 4;

  bf16x8 bfrag[4];
  if constexpr (F32IN) {
    int brow = row0 + m;
    if (brow >= N) brow = N - 1;
    const float* xrow = xf + (size_t)brow * 128 + q * 8;
#pragma unroll
    for (int kt = 0; kt < 4; ++kt) {
      float4 u0 = *(const float4*)(xrow + kt * 32);
      float4 u1 = *(const float4*)(xrow + kt * 32 + 4);
      bf16x8 f;
      f[0] = (short)f2bf(u0.x); f[1] = (short)f2bf(u0.y);
      f[2] = (short)f2bf(u0.z); f[3] = (short)f2bf(u0.w);
      f[4] = (short)f2bf(u1.x); f[5] = (short)f2bf(u1.y);
      f[6] = (short)f2bf(u1.z); f[7] = (short)f2bf(u1.w);
      bfrag[kt] = f;
    }
  } else {
    const unsigned short* xrow = xpack + (size_t)(row0 >> 4) * 2048 + lane * 8;
#pragma unroll
    for (int kt = 0; kt < 4; ++kt) bfrag[kt] = *(const bf16x8*)(xrow + kt * 512);
  }

  f32x4 accL[8], accR[8];
#pragma unroll
  for (int jt = 0; jt < 8; ++jt) {
    accL[jt] = (f32x4){0.f, 0.f, 0.f, 0.f};
    accR[jt] = (f32x4){0.f, 0.f, 0.f, 0.f};
  }

#pragma unroll
  for (int kt = 0; kt < 4; ++kt) {
#pragma unroll
    for (int jt = 0; jt < 8; ++jt) {
      bf16x8 aL = *(const bf16x8*)(WL + (size_t)(jt * 4 + kt) * 512 + lane * 8);
      accL[jt] = __builtin_amdgcn_mfma_f32_16x16x32_bf16(aL, bfrag[kt], accL[jt], 0, 0, 0);
      bf16x8 aR = *(const bf16x8*)(WR + (size_t)(jt * 4 + kt) * 512 + lane * 8);
      accR[jt] = __builtin_amdgcn_mfma_f32_16x16x32_bf16(aR, bfrag[kt], accR[jt], 0, 0, 0);
    }
  }

  // ---- L: pack+bias -> LDS transpose -> coalesced stores ----
#pragma unroll
  for (int jt = 0; jt < 8; ++jt) {
    float4 bs = *(const float4*)&bl[jt * 16 + q * 4];
    uint2 p;
    p.x = (unsigned int)f2bf(accL[jt][0] + bs.x) | ((unsigned int)f2bf(accL[jt][1] + bs.y) << 16);
    p.y = (unsigned int)f2bf(accL[jt][2] + bs.z) | ((unsigned int)f2bf(accL[jt][3] + bs.w) << 16);
    *(uint2*)&sld[wave][m * 128 + jt * 16 + q * 4] = p;
  }
#pragma unroll
  for (int r = 0; r < 4; ++r) {
    uint4 vv = *(const uint4*)&sld[wave][r * 512 + lane * 8];
    int node = row0 + r * 4 + (lane >> 4);
    if (node < N) *(uint4*)(xlb + (size_t)row0 * 128 + r * 512 + lane * 8) = vv;
  }
  // ---- R: reuse LDS ----
#pragma unroll
  for (int jt = 0; jt < 8; ++jt) {
    float4 bs = *(const float4*)&br[jt * 16 + q * 4];
    uint2 p;
    p.x = (unsigned int)f2bf(accR[jt][0] + bs.x) | ((unsigned int)f2bf(accR[jt][1] + bs.y) << 16);
    p.y = (unsigned int)f2bf(accR[jt][2] + bs.z) | ((unsigned int)f2bf(accR[jt][3] + bs.w) << 16);
    *(uint2*)&sld[wave][m * 128 + jt * 16 + q * 4] = p;
  }
#pragma unroll
  for (int r = 0; r < 4; ++r) {
    uint4 vv = *(const uint4*)&sld[wave][r * 512 + lane * 8];
    int node = row0 + r * 4 + (lane >> 4);
    if (node < N) *(uint4*)(xrb + (size_t)row0 * 128 + r * 512 + lane * 8) = vv;
  }
}

// ---------------- fused: score + softmax(exp2) + weighted agg + epilogue ----------------
// one wave per node; lanes 0-31 = edge p, lanes 32-63 = edge p+1 (same node);
// each lane owns 4 channels c = (lane&31)*4; head group = 8 lanes.
// (R11 core verbatim; only the xnext write address is fragment-packed.)
__global__ __launch_bounds__(256) void k_agg(const unsigned short* __restrict__ xlb,
                                             const unsigned short* __restrict__ xrb,
                                             const float4* __restrict__ e4,
                                             const int* __restrict__ offs,
                                             const float* __restrict__ scoreTab,
                                             const float* __restrict__ bo,
                                             const float* __restrict__ lng, const float* __restrict__ lnb,
                                             unsigned short* __restrict__ xnext_pack,
                                             float* __restrict__ emb, int last, int N) {
  int w = (blockIdx.x * blockDim.x + threadIdx.x) >> 6;
  if (w >= N) return;
  int lane = threadIdx.x & 63;
  int half = lane >> 5;
  int sl = lane & 31;
  int c = sl * 4;
  unsigned int c2 = (unsigned int)(c * 2);  // byte offset into bf16 row
  int beg = offs[w], end = offs[w + 1];
  int cnt = end - beg;

  // packed per-lane params as float2 halves (channels 01 / 23)
  f32x2 xr01, xr23, wea01, wea23, web01, web23, wec01, wec23, at01, at23;
  {
    const float4* tp = (const float4*)(scoreTab + (size_t)sl * 16);
    float4 pa = tp[0], pb = tp[1], pc = tp[2], pt = tp[3];
    wea01[0] = pa.x; wea01[1] = pa.y; wea23[0] = pa.z; wea23[1] = pa.w;
    web01[0] = pb.x; web01[1] = pb.y; web23[0] = pb.z; web23[1] = pb.w;
    wec01[0] = pc.x; wec01[1] = pc.y; wec23[0] = pc.z; wec23[1] = pc.w;
    at01[0] = pt.x; at01[1] = pt.y; at23[0] = pt.z; at23[1] = pt.w;
    uint2 vr = *(const uint2*)&xrb[(size_t)w * 128 + c];
    xr01[0] = __uint_as_float(vr.x << 16);
    xr01[1] = __uint_as_float(vr.x & 0xffff0000u);
    xr23[0] = __uint_as_float(vr.y << 16);
    xr23[1] = __uint_as_float(vr.y & 0xffff0000u);
  }

  const char* e4B = (const char*)e4;
  const char* xlB = (const char*)xlb;

  float l = 0.f;
  f32x2 acc01 = {0.f, 0.f}, acc23 = {0.f, 0.f};

  unsigned int lastoff = (unsigned int)(end - 1) << 4;
  int T = (cnt + 1) >> 1;  // pair iterations

  // ---- pipeline prologue: records for pairs 0..2, gathers for pairs 0..1 ----
  unsigned int o0 = (unsigned int)(beg + half) << 4;
  if (o0 > lastoff) o0 = lastoff;  // cnt==1, half 1 clamps
  unsigned int o1 = o0 + 32u;
  if (o1 > lastoff) o1 = lastoff;
  unsigned int o2 = o1 + 32u;
  if (o2 > lastoff) o2 = lastoff;
  float4 e0 = *(const float4*)(e4B + o0);
  float4 e1 = *(const float4*)(e4B + o1);
  float4 e2 = *(const float4*)(e4B + o2);
  uint2 g0 = *(const uint2*)(xlB + ((unsigned int)__float_as_int(e0.w) + c2));
  uint2 g1 = *(const uint2*)(xlB + ((unsigned int)__float_as_int(e1.w) + c2));
  unsigned int offP = o2;

  // one edge: unpack gather, score (packed f32), exp2, accumulate.
  auto compute = [&](const float4& e, uint2 v, bool valid) {
    f32x2 xl01, xl23;
    xl01[0] = __uint_as_float(v.x << 16);
    xl01[1] = __uint_as_float(v.x & 0xffff0000u);
    xl23[0] = __uint_as_float(v.y << 16);
    xl23[1] = __uint_as_float(v.y & 0xffff0000u);
    f32x2 ex = {e.x, e.x}, ey = {e.y, e.y}, ez = {e.z, e.z};
    f32x2 t01 = __builtin_elementwise_fma(wea01, ex,
                  __builtin_elementwise_fma(web01, ey,
                    __builtin_elementwise_fma(wec01, ez, xr01 + xl01)));
    f32x2 t23 = __builtin_elementwise_fma(wea23, ex,
                  __builtin_elementwise_fma(web23, ey,
                    __builtin_elementwise_fma(wec23, ez, xr23 + xl23)));
    t01 = __builtin_elementwise_max(t01, t01 * 0.2f);
    t23 = __builtin_elementwise_max(t23, t23 * 0.2f);
    f32x2 d2 = __builtin_elementwise_fma(t01, at01, t23 * at23);
    float s = d2[0] + d2[1];
    float wgt = __builtin_amdgcn_exp2f(dpp_sum8(s));
    if (!valid) wgt = 0.f;
    l += wgt;
    f32x2 w2 = {wgt, wgt};
    acc01 = __builtin_elementwise_fma(xl01, w2, acc01);
    acc23 = __builtin_elementwise_fma(xl23, w2, acc23);
  };

  // ---- steady state: record(i+3), gather(i+2), compute(i) ----
#pragma unroll 2
  for (int it = 0; it < T - 3; ++it) {
    unsigned int o3 = offP + 32u;
    if (o3 > lastoff) o3 = lastoff;
    float4 e3 = *(const float4*)(e4B + o3);
    uint2 g2 = *(const uint2*)(xlB + ((unsigned int)__float_as_int(e2.w) + c2));
    compute(e0, g0, true);
    e0 = e1; e1 = e2; e2 = e3;
    g0 = g1; g1 = g2;
    offP = o3;
  }
  if (T >= 3) {  // pair T-3: issue last gather, compute
    uint2 g2 = *(const uint2*)(xlB + ((unsigned int)__float_as_int(e2.w) + c2));
    compute(e0, g0, true);
    e0 = e1; e1 = e2;
    g0 = g1; g1 = g2;
  }
  if (T >= 2) {  // pair T-2 (always fully valid)
    compute(e0, g0, true);
    e0 = e1;
    g0 = g1;
  }
  {  // pair T-1 (masked: odd cnt leaves half==1 invalid)
    int idx = 2 * (T - 1) + half;
    compute(e0, g0, idx < cnt);
  }

  // combine halves
  l += __shfl_xor(l, 32);
  float a0 = acc01[0]; a0 += __shfl_xor(a0, 32);
  float a1 = acc01[1]; a1 += __shfl_xor(a1, 32);
  float a2 = acc23[0]; a2 += __shfl_xor(a2, 32);
  float a3 = acc23[1]; a3 += __shfl_xor(a3, 32);

  float inv = 1.0f / l;
  f32x4 o4;
  const float4 bo4 = *(const float4*)&bo[c];
  o4[0] = a0 * inv + bo4.x;
  o4[1] = a1 * inv + bo4.y;
  o4[2] = a2 * inv + bo4.z;
  o4[3] = a3 * inv + bo4.w;

  if (last) {
    if (half == 0) {
      float4 st = {o4[0], o4[1], o4[2], o4[3]};
      *(float4*)&emb[(size_t)w * 128 + c] = st;
    }
  } else {
    f32x4 r;
    r[0] = fmaxf(o4[0], 0.f);
    r[1] = fmaxf(o4[1], 0.f);
    r[2] = fmaxf(o4[2], 0.f);
    r[3] = fmaxf(o4[3], 0.f);
    float s = r[0] + r[1] + r[2] + r[3];
    s += __shfl_xor(s, 1);
    s += __shfl_xor(s, 2);
    s += __shfl_xor(s, 4);
    s += __shfl_xor(s, 8);
    s += __shfl_xor(s, 16);
    float mu = s * 0.0078125f;  // /128
    f32x4 d;
    d[0] = r[0] - mu;
    d[1] = r[1] - mu;
    d[2] = r[2] - mu;
    d[3] = r[3] - mu;
    float v2 = d[0] * d[0] + d[1] * d[1] + d[2] * d[2] + d[3] * d[3];
    v2 += __shfl_xor(v2, 1);
    v2 += __shfl_xor(v2, 2);
    v2 += __shfl_xor(v2, 4);
    v2 += __shfl_xor(v2, 8);
    v2 += __shfl_xor(v2, 16);
    float var = v2 * 0.0078125f;
    float rstd = rsqrtf(var + LN_EPS);
    if (half == 0) {
      const float4 g4 = *(const float4*)&lng[c];
      const float4 b4 = *(const float4*)&lnb[c];
      float o0 = d[0] * rstd * g4.x + b4.x;
      float o1 = d[1] * rstd * g4.y + b4.y;
      float o2 = d[2] * rstd * g4.z + b4.z;
      float o3 = d[3] * rstd * g4.w + b4.w;
      uint2 pack;
      pack.x = (unsigned int)f2bf(o0) | ((unsigned int)f2bf(o1) << 16);
      pack.y = (unsigned int)f2bf(o2) | ((unsigned int)f2bf(o3) << 16);
      // fragment-packed write: node w -> block B=w>>4, m=w&15;
      // channels c..c+3: kt=sl>>3, q=(sl>>1)&3, half8=(sl&1)*4
      int kt = sl >> 3;
      int qq = (sl >> 1) & 3;
      size_t elem = (size_t)(w >> 4) * 2048 + kt * 512 + (qq * 16 + (w & 15)) * 8 + (sl & 1) * 4;
      *(uint2*)&xnext_pack[elem] = pack;
    }
  }
}

// ---------------- graph max-pool (relu implicit: atomicMax vs 0-init) ----------------
__global__ void k_pool(const float* __restrict__ emb, const int* __restrict__ batch,
                       float* __restrict__ pooled, int N) {
  int c = threadIdx.x & 127;
  int half = threadIdx.x >> 7;
  int base = blockIdx.x * 64 + half;
  int limit = min(blockIdx.x * 64 + 64, N);
  float cur = 0.f;
  int curg = -1;
  for (int n = base; n < limit; n += 2) {
    int g = batch[n];
    if (g != curg) {
      if (curg >= 0) atomicMax((unsigned int*)&pooled[curg * 128 + c], __float_as_uint(cur));
      curg = g;
      cur = 0.f;
    }
    cur = fmaxf(cur, emb[(size_t)n * 128 + c]);
  }
  if (curg >= 0) atomicMax((unsigned int*)&pooled[curg * 128 + c], __float_as_uint(cur));
}

// ---------------- MLP: 128 -> 32 -> 32 -> 32 -> 1 ----------------
__global__ void k_mlp(const float* __restrict__ pooled,
                      const float* __restrict__ pw1, const float* __restrict__ pb1,
                      const float* __restrict__ pw2, const float* __restrict__ pb2,
                      const float* __restrict__ pw3, const float* __restrict__ pb3,
                      const float* __restrict__ pw4, const float* __restrict__ pb4,
                      float* __restrict__ out) {
  int g = blockIdx.x;
  int t = threadIdx.x;  // 64 threads
  __shared__ float buf1[32], buf2[32];
  if (t < 32) {
    float acc = pb1[t];
    for (int k = 0; k < 128; ++k) acc += pw1[t * 128 + k] * pooled[g * 128 + k];
    buf1[t] = fmaxf(acc, 0.f);
  }
  __syncthreads();
  if (t < 32) {
    float acc = pb2[t];
    for (int k = 0; k < 32; ++k) acc += pw2[t * 32 + k] * buf1[k];
    buf2[t] = fmaxf(acc, 0.f);
  }
  __syncthreads();
  if (t < 32) {
    float acc = pb3[t];
    for (int k = 0; k < 32; ++k) acc += pw3[t * 32 + k] * buf2[k];
    buf1[t] = fmaxf(acc, 0.f);
  }
  __syncthreads();
  if (t == 0) {
    float acc = pb4[0];
    for (int k = 0; k < 32; ++k) acc += pw4[k] * buf1[k];
    out[g] = acc;
  }
}

// ---------------------------------------------------------------------------

extern "C" void kernel_launch(void* const* d_in, const int* in_sizes, int n_in,
                              void* d_out, int out_size, void* d_ws, size_t ws_size,
                              hipStream_t stream) {
  const float* x_in = (const float*)d_in[0];
  const int* ei = (const int*)d_in[1];
  const int* batch = (const int*)d_in[2];
  const float* ea = (const float*)d_in[3];

  const int N = in_sizes[0] / 128;
  const int E = in_sizes[1] / 2;
  const int EP = E + N;
  const int G = out_size - N * 128;
  const int NBUK = (N + 255) / 256;
  const int NBINA = (E + CHUNK - 1) / CHUNK;

  const float *Wl[3], *bl[3], *Wr[3], *br[3], *We[3], *att[3], *bo[3];
  for (int l = 0; l < 3; ++l) {
    Wl[l] = (const float*)d_in[4 + 7 * l];
    bl[l] = (const float*)d_in[5 + 7 * l];
    Wr[l] = (const float*)d_in[6 + 7 * l];
    br[l] = (const float*)d_in[7 + 7 * l];
    We[l] = (const float*)d_in[8 + 7 * l];
    att[l] = (const float*)d_in[9 + 7 * l];
    bo[l] = (const float*)d_in[10 + 7 * l];
  }
  const float* lng[2] = {(const float*)d_in[25], (const float*)d_in[27]};
  const float* lnb[2] = {(const float*)d_in[26], (const float*)d_in[28]};
  const float* pw1 = (const float*)d_in[29];
  const float* pb1 = (const float*)d_in[30];
  const float* pw2 = (const float*)d_in[31];
  const float* pb2 = (const float*)d_in[32];
  const float* pw3 = (const float*)d_in[33];
  const float* pb3 = (const float*)d_in[34];
  const float* pw4 = (const float*)d_in[35];
  const float* pb4 = (const float*)d_in[36];

  char* base = (char*)d_ws;
  size_t cur = 0;
  auto carve = [&](size_t bytes) -> char* {
    char* p = base + cur;
    cur += (bytes + 255) & ~(size_t)255;
    return p;
  };
  unsigned short* xlb = (unsigned short*)carve((size_t)N * 128 * 2);
  unsigned short* xrb = (unsigned short*)carve((size_t)N * 128 * 2);
  // xpack: fragment-packed inter-layer activations; +1 block slack for tail
  unsigned short* xpack = (unsigned short*)carve(((size_t)((N + 15) / 16) + 1) * 2048 * 2);
  unsigned short* Wb = (unsigned short*)carve((size_t)6 * 16384 * 2);
  float4* e4 = (float4*)carve((size_t)(EP + 8) * 16);  // +8 pad records
  float4* staged = (float4*)carve((size_t)NBUK * BCAP * 16);
  int* offs = (int*)carve((size_t)(N + 1) * 4);
  int* gcnt = (int*)carve((size_t)NBUK * 4);
  float* scoreTab = (float*)carve((size_t)3 * 512 * 4);
  float* pooled = (float*)carve((size_t)G * 128 * 4);

  float* emb_out = (float*)d_out;
  float* mlp_out = (float*)d_out + (size_t)N * 128;

  hipMemsetAsync(gcnt, 0, (size_t)NBUK * 4, stream);
  hipMemsetAsync(pooled, 0, (size_t)G * 128 * 4, stream);

  // packed prologue: binA blocks + packed-convW blocks + 1 pack block
  k_pre<<<NBINA + 48 + 1, 256, 0, stream>>>(ei, ea, gcnt, staged, E, NBUK, NBINA,
                                            Wl[0], Wr[0], Wl[1], Wr[1], Wl[2], Wr[2], Wb,
                                            We[0], att[0], We[1], att[1], We[2], att[2],
                                            scoreTab);
  k_binB<<<NBUK, 256, 0, stream>>>(staged, gcnt, e4, offs, N, NBUK, EP);

  for (int l = 0; l < 3; ++l) {
    dim3 ggrid((N + 63) / 64);
    if (l == 0) {
      k_gemm_fused<true><<<ggrid, 256, 0, stream>>>(x_in, xpack, Wb, bl[0], br[0], xlb, xrb, N);
    } else {
      k_gemm_fused<false><<<ggrid, 256, 0, stream>>>(nullptr, xpack, Wb + (size_t)l * 32768,
                                                     bl[l], br[l], xlb, xrb, N);
    }
    int last = (l == 2) ? 1 : 0;
    const float* g = last ? bo[l] : lng[l];
    const float* b = last ? bo[l] : lnb[l];
    k_agg<<<(N * 64 + 255) / 256, 256, 0, stream>>>(xlb, xrb, e4, offs,
                                                    scoreTab + (size_t)l * 512,
                                                    bo[l], g, b,
                                                    xpack, emb_out, last, N);
  }

  k_pool<<<(N + 63) / 64, 256, 0, stream>>>(emb_out, batch, pooled, N);
  k_mlp<<<G, 64, 0, stream>>>(pooled, pw1, pb1, pw2, pb2, pw3, pb3, pw4, pb4, mlp_out);
}